// Round 5
// baseline (769.674 us; speedup 1.0000x reference)
//
#include <hip/hip_runtime.h>
#include <hip/hip_bf16.h>

#define NUM_USERS 100000
#define NUM_ITEMS 50000
#define EMBED_DIM 64
#define N_NODES   150000                 // NUM_USERS + NUM_ITEMS
#define ROW_SHIFT 9                      // 512 rows per bucket
#define ROWS_PER_BUCKET 512
#define B_BUCKETS ((N_NODES + ROWS_PER_BUCKET - 1) / ROWS_PER_BUCKET)   // 293

typedef unsigned short ushort_t;
typedef unsigned int uint_t;

__device__ __forceinline__ float bf16_to_f32(ushort_t u) {
    return __uint_as_float(((unsigned)u) << 16);
}
__device__ __forceinline__ ushort_t f32_to_bf16(float f) {
    return __builtin_bit_cast(ushort_t, __float2bfloat16(f));   // RNE
}

// ---------------------------------------------------------------------------
// k_cc: heterogeneous grid. First g_conv blocks: fp32->bf16 ego convert
// (unchanged from k_bin2). Remaining blocks: per-row edge counting via
// global atomicAdd into rc[N_NODES] (600 KB, L2-resident). 4 edges/thread,
// int4 coalesced loads. Replaces the LDS-histogram + block-scan + staged
// binning of the old k_bin2 (which, with k_scatter2b, cost ~2x one SpMM).
// ---------------------------------------------------------------------------
__global__ void __launch_bounds__(512) k_cc(const float* __restrict__ ue,
                                            const float* __restrict__ ie,
                                            ushort_t* __restrict__ xb,
                                            const int* __restrict__ rows,
                                            int* __restrict__ rc,
                                            int nnz, int g_conv) {
    int t = threadIdx.x;
    if ((int)blockIdx.x < g_conv) {
        // ---- convert: fp32 ego table -> bf16 (float4 granularity) ----
        int i = blockIdx.x * 512 + t;
        const int n4 = (N_NODES * EMBED_DIM) / 4;
        if (i >= n4) return;
        const int usplit = (NUM_USERS * EMBED_DIM) / 4;
        float4 f = (i < usplit) ? ((const float4*)ue)[i] : ((const float4*)ie)[i - usplit];
        ushort4 o;
        o.x = f32_to_bf16(f.x);
        o.y = f32_to_bf16(f.y);
        o.z = f32_to_bf16(f.z);
        o.w = f32_to_bf16(f.w);
        ((ushort4*)xb)[i] = o;
        return;
    }
    // ---- count: 4 edges/thread, int4 loads (nnz % 4 == 0 in practice;
    // guarded per-element for safety) ----
    int idx = ((int)(blockIdx.x - g_conv) * 512 + t) * 4;
    if (idx + 3 < nnz) {
        int4 r4 = *(const int4*)(rows + idx);
        atomicAdd(&rc[r4.x], 1);
        atomicAdd(&rc[r4.y], 1);
        atomicAdd(&rc[r4.z], 1);
        atomicAdd(&rc[r4.w], 1);
    } else {
        for (int k = idx; k < nnz; k++) atomicAdd(&rc[rows[k]], 1);
    }
}

// ---------------------------------------------------------------------------
// k_scanb: one block per bucket (512 rows). Exclusive scan of rc within the
// bucket -> per-row ranges {beg,end} and the place-cursor cur[row]=beg.
// cv keeps the per-bucket padded layout (bucket b starts at b*cap), which
// preserves k_spmm's tail-overread slack (cap has 16-sigma margin).
// ---------------------------------------------------------------------------
__global__ void __launch_bounds__(512) k_scanb(const int* __restrict__ rc,
                                               int2* __restrict__ ranges,
                                               int* __restrict__ cur, int cap) {
    __shared__ int sc[ROWS_PER_BUCKET];
    int b = blockIdx.x;
    int t = threadIdx.x;
    int row = (b << ROW_SHIFT) + t;
    int c = (row < N_NODES) ? rc[row] : 0;
    sc[t] = c;
    __syncthreads();
    for (int d = 1; d < ROWS_PER_BUCKET; d <<= 1) {
        int y = (t >= d) ? sc[t - d] : 0;
        __syncthreads();
        sc[t] += y;
        __syncthreads();
    }
    int excl = sc[t] - c;
    int beg = b * cap + excl;
    if (row < N_NODES) {
        ranges[row] = make_int2(beg, beg + c);
        cur[row] = beg;
    }
}

// ---------------------------------------------------------------------------
// k_place: direct placement. For each edge: pos = atomicAdd(&cur[row],1);
// cv[pos] = {col, val}. Scattered 8B writes land in L2/L3 (cv = 43 MB fits
// Infinity Cache; every line is eventually fully written). Capacity guard
// (never hits at 16-sigma margin) prevents cross-bucket corruption.
// Within-row edge order is nondeterministic — fp32 sum reorder, same class
// of tolerance as the old bucket scheme (also nondeterministic).
// ---------------------------------------------------------------------------
__global__ void __launch_bounds__(512) k_place(const int* __restrict__ rows,
                                               const int* __restrict__ cols,
                                               const float* __restrict__ vals,
                                               int* __restrict__ cur,
                                               int2* __restrict__ cv,
                                               int nnz, int cap) {
    int idx = ((int)blockIdx.x * 512 + (int)threadIdx.x) * 4;
    if (idx + 3 < nnz) {
        int4   r4 = *(const int4*)(rows + idx);
        int4   c4 = *(const int4*)(cols + idx);
        float4 v4 = *(const float4*)(vals + idx);
        int p0 = atomicAdd(&cur[r4.x], 1);
        int p1 = atomicAdd(&cur[r4.y], 1);
        int p2 = atomicAdd(&cur[r4.z], 1);
        int p3 = atomicAdd(&cur[r4.w], 1);
        if (p0 < ((r4.x >> ROW_SHIFT) + 1) * cap) cv[p0] = make_int2(c4.x, __float_as_int(v4.x));
        if (p1 < ((r4.y >> ROW_SHIFT) + 1) * cap) cv[p1] = make_int2(c4.y, __float_as_int(v4.y));
        if (p2 < ((r4.z >> ROW_SHIFT) + 1) * cap) cv[p2] = make_int2(c4.z, __float_as_int(v4.z));
        if (p3 < ((r4.w >> ROW_SHIFT) + 1) * cap) cv[p3] = make_int2(c4.w, __float_as_int(v4.w));
    } else {
        for (int k = idx; k < nnz; k++) {
            int r = rows[k];
            int pos = atomicAdd(&cur[r], 1);
            if (pos < ((r >> ROW_SHIFT) + 1) * cap)
                cv[pos] = make_int2(cols[k], __float_as_int(vals[k]));
        }
    }
}

// ---------------------------------------------------------------------------
// R16 readlane-broadcast SpMM row body (UNCHANGED — verified 87.5 us).
// Edge stream: lane l loads edge beg+l with ONE coalesced global_load_dwordx2
// (64 edges / 512B / one vmcnt entry). Invalid lanes clamp col->0 / val->0
// (row 0 stays L1-hot, contributes 0; also shields uninitialized cv slack).
// Each edge broadcast via v_readlane; gathers issue in a 32-wide window then
// drain in-order. Overreads stay inside the bucket's padded slack.
// ---------------------------------------------------------------------------
#define ISSUE8(R, J0)                                                         \
    _Pragma("unroll")                                                         \
    for (int j = 0; j < 8; j++) {                                             \
        int sc = __builtin_amdgcn_readlane(vc, (J0) + j);                     \
        R[j] = xb[((size_t)(uint_t)sc << 6) + lane];                          \
    }

#define CONS8(R, J0)                                                          \
    _Pragma("unroll")                                                         \
    for (int j = 0; j < 8; j++) {                                             \
        float sv = __uint_as_float((uint_t)__builtin_amdgcn_readlane(vv, (J0) + j)); \
        acc += sv * __uint_as_float((uint_t)R[j] << 16);                      \
    }

__device__ __forceinline__ float spmm_row_rl(int beg, int end, int lane,
                                             const int2* __restrict__ cv,
                                             const ushort_t* __restrict__ xb) {
    float acc = 0.f;
#pragma unroll 1
    for (int b = beg; b < end; b += 64) {
        int2 ed = cv[b + lane];              // coalesced 512B, 1 vmcnt entry
        bool lv = (b + lane) < end;
        int vc = lv ? ed.x : 0;              // per-lane clamp (2 cndmask)
        int vv = lv ? ed.y : 0;
        int rem = end - b;                   // wave-uniform
        if (rem > 64) rem = 64;

        ushort_t q0[8], q1[8], q2[8], q3[8];
        // ---- half 0: edges 0..31 ----
        ISSUE8(q0, 0)
        if (rem > 8)  { ISSUE8(q1, 8)  }
        if (rem > 16) { ISSUE8(q2, 16) }
        if (rem > 24) { ISSUE8(q3, 24) }
        CONS8(q0, 0)
        if (rem > 8)  { CONS8(q1, 8)  }
        if (rem > 16) { CONS8(q2, 16) }
        if (rem > 24) { CONS8(q3, 24) }
        // ---- half 1: edges 32..63 ----
        if (rem > 32) {
            ISSUE8(q0, 32)
            if (rem > 40) { ISSUE8(q1, 40) }
            if (rem > 48) { ISSUE8(q2, 48) }
            if (rem > 56) { ISSUE8(q3, 56) }
            CONS8(q0, 32)
            if (rem > 40) { CONS8(q1, 40) }
            if (rem > 48) { CONS8(q2, 48) }
            if (rem > 56) { CONS8(q3, 56) }
        }
    }
    return acc;
}

__global__ void k_spmm(const int2* __restrict__ ranges, const int2* __restrict__ cv,
                       const ushort_t* __restrict__ xb, ushort_t* __restrict__ out) {
    int row = (blockIdx.x * blockDim.x + threadIdx.x) >> 6;
    int lane = threadIdx.x & 63;
    if (row >= N_NODES) return;
    row = __builtin_amdgcn_readfirstlane(row);
    int2 rng = ranges[row];
    int beg = __builtin_amdgcn_readfirstlane(rng.x);
    int end = __builtin_amdgcn_readfirstlane(rng.y);
    float a = spmm_row_rl(beg, end, lane, cv, xb);
    out[(size_t)row * 64 + lane] = f32_to_bf16(a);   // 64 lanes x 2B = 128B
}

// ---------------------------------------------------------------------------
// k_last (UNCHANGED): one wave per batch element. Layer-3 rows for BOTH the
// user node and item node, gathers ego(fp32)+xbA+xbB, emits the dot.
// ---------------------------------------------------------------------------
__global__ void k_last(const int2* __restrict__ ranges, const int2* __restrict__ cv,
                       const int* __restrict__ users, const int* __restrict__ items,
                       const float* __restrict__ ue, const float* __restrict__ ie,
                       const ushort_t* __restrict__ xbA, const ushort_t* __restrict__ xbB,
                       float* __restrict__ out, int batch) {
    int w = (blockIdx.x * blockDim.x + threadIdx.x) >> 6;
    int lane = threadIdx.x & 63;
    if (w >= batch) return;

    int uu = __builtin_amdgcn_readfirstlane(users[w]);
    int ii = __builtin_amdgcn_readfirstlane(items[w]);
    int row_u = uu;
    int row_i = NUM_USERS + ii;

    // layer-3 contributions (source = xbB)
    int2 ru = ranges[row_u];
    float a_u = spmm_row_rl(__builtin_amdgcn_readfirstlane(ru.x),
                            __builtin_amdgcn_readfirstlane(ru.y), lane, cv, xbB);
    int2 ri = ranges[row_i];
    float a_i = spmm_row_rl(__builtin_amdgcn_readfirstlane(ri.x),
                            __builtin_amdgcn_readfirstlane(ri.y), lane, cv, xbB);

    float e_u = ue[(size_t)uu * EMBED_DIM + lane];
    float e_i = ie[(size_t)ii * EMBED_DIM + lane];
    float Au = bf16_to_f32(xbA[(size_t)row_u * 64 + lane]);
    float Bu = bf16_to_f32(xbB[(size_t)row_u * 64 + lane]);
    float Ai = bf16_to_f32(xbA[(size_t)row_i * 64 + lane]);
    float Bi = bf16_to_f32(xbB[(size_t)row_i * 64 + lane]);

    float ux = e_u + Au + Bu + a_u;
    float ix = e_i + Ai + Bi + a_i;

    float p = ux * ix;
#pragma unroll
    for (int d = 32; d > 0; d >>= 1) p += __shfl_down(p, d, 64);
    if (lane == 0) out[w] = p * (1.0f / 16.0f);   // 1/16 mean^2 scale
}

// ---------------------------------------------------------------------------

extern "C" void kernel_launch(void* const* d_in, const int* in_sizes, int n_in,
                              void* d_out, int out_size, void* d_ws, size_t ws_size,
                              hipStream_t stream) {
    const int*   users    = (const int*)  d_in[0];
    const int*   items    = (const int*)  d_in[1];
    const int*   adj_rows = (const int*)  d_in[2];
    const int*   adj_cols = (const int*)  d_in[3];
    const float* adj_vals = (const float*)d_in[4];
    const float* user_emb = (const float*)d_in[5];
    const float* item_emb = (const float*)d_in[6];
    float* out = (float*)d_out;

    const int batch = in_sizes[0];
    const int nnz   = in_sizes[2];

    // fixed bucket capacity: mean * 9/8, rounded up to 64 (16-sigma margin)
    int cap = ((nnz / B_BUCKETS) * 9 + 7) / 8;
    cap = (cap + 63) & ~63;
    const size_t padded = (size_t)B_BUCKETS * cap;   // ~5.4M entries

    char* p = (char*)d_ws;
    auto alloc = [&](size_t bytes) -> char* {
        char* r = p;
        p += (bytes + 255) & ~(size_t)255;
        return r;
    };
    const size_t xb_bytes = (size_t)N_NODES * EMBED_DIM * 2;       // 19.2 MB
    int2*     ranges = (int2*) alloc((size_t)N_NODES * 8);
    int*      rc     = (int*)  alloc((size_t)N_NODES * 4);         // counts
    int*      cur    = (int*)  alloc((size_t)N_NODES * 4);         // cursors
    int2*     cv     = (int2*) alloc(padded * 8);                  // padded CSR
    ushort_t* xbA    = (ushort_t*)alloc(xb_bytes);
    ushort_t* xbB    = (ushort_t*)alloc(xb_bytes);
    ushort_t* xb_ego = (ushort_t*)alloc(xb_bytes);

    const int g_conv  = ((N_NODES * EMBED_DIM / 4) + 511) / 512;   // 4688
    const int g_edge4 = (nnz + 2047) / 2048;                       // 4 edges/thread
    const int g_nodes = (N_NODES + 3) / 4;                         // 4 waves/block
    const int g_batch = (batch + 3) / 4;

    // ---- build: count -> bucket-scan -> direct place ----
    hipMemsetAsync(rc, 0, (size_t)N_NODES * 4, stream);
    k_cc<<<g_conv + g_edge4, 512, 0, stream>>>(user_emb, item_emb, xb_ego,
                                               adj_rows, rc, nnz, g_conv);
    k_scanb<<<B_BUCKETS, 512, 0, stream>>>(rc, ranges, cur, cap);
    k_place<<<g_edge4, 512, 0, stream>>>(adj_rows, adj_cols, adj_vals,
                                         cur, cv, nnz, cap);

    // ---- layer 1: xbA = A * ego ----
    k_spmm<<<g_nodes, 256, 0, stream>>>(ranges, cv, xb_ego, xbA);

    // ---- layer 2: xbB = A * xbA ----
    k_spmm<<<g_nodes, 256, 0, stream>>>(ranges, cv, xbA, xbB);

    // ---- layer 3 (batch rows only) + gather + dot, fused ----
    k_last<<<g_batch, 256, 0, stream>>>(ranges, cv, users, items,
                                        user_emb, item_emb, xbA, xbB, out, batch);
}

// Round 7
// 692.835 us; speedup vs baseline: 1.1109x; 1.1109x over previous
//
#include <hip/hip_runtime.h>
#include <hip/hip_bf16.h>

#define NUM_USERS 100000
#define NUM_ITEMS 50000
#define EMBED_DIM 64
#define N_NODES   150000                 // NUM_USERS + NUM_ITEMS
#define ROW_SHIFT 9                      // 512 rows per bucket
#define ROWS_PER_BUCKET 512
#define B_BUCKETS ((N_NODES + ROWS_PER_BUCKET - 1) / ROWS_PER_BUCKET)   // 293
#define NBP 512                          // padded bucket-array size
#define BIN_CHUNK 2048                   // edges per bin block (4/thread @512)
#define PLACE_CHUNK 2048                 // staging entries per k_rplace block
#define COL_MASK 0x3FFFF                 // 18 bits for col (N_NODES < 262144)

typedef unsigned short ushort_t;
typedef unsigned int uint_t;

__device__ __forceinline__ float bf16_to_f32(ushort_t u) {
    return __uint_as_float(((unsigned)u) << 16);
}
__device__ __forceinline__ ushort_t f32_to_bf16(float f) {
    return __builtin_bit_cast(ushort_t, __float2bfloat16(f));   // RNE
}

// ---------------------------------------------------------------------------
// k_bin2: heterogeneous grid. First g_conv blocks: fp32->bf16 ego convert.
// Remaining blocks: LDS-binned staging into FIXED-CAPACITY bucket regions
// (cap entries per bucket; cursor[b] counts fill). The LDS compaction makes
// staging writes bucket-run-contiguous (~7-entry runs) — this is what keeps
// write amplification low (R17's direct scatter hit 8x amp, 360 us).
// R18: also counts edges per ROW via global atomicAdd into rc[] (600 KB,
// L2-resident; fire-and-forget). Staging entry: int2 {col | lrow<<18, val}.
// ---------------------------------------------------------------------------
__global__ void __launch_bounds__(512) k_bin2(const float* __restrict__ ue,
                                              const float* __restrict__ ie,
                                              ushort_t* __restrict__ xb,
                                              const int* __restrict__ rows,
                                              const int* __restrict__ cols,
                                              const float* __restrict__ vals,
                                              int* __restrict__ cursor,
                                              int* __restrict__ rc,
                                              int2* __restrict__ staging,
                                              int nnz, int cap, int g_conv) {
    int t = threadIdx.x;
    if ((int)blockIdx.x < g_conv) {
        // ---- convert: fp32 ego table -> bf16 (float4 granularity) ----
        int i = blockIdx.x * 512 + t;
        const int n4 = (N_NODES * EMBED_DIM) / 4;
        if (i >= n4) return;
        const int usplit = (NUM_USERS * EMBED_DIM) / 4;
        float4 f = (i < usplit) ? ((const float4*)ue)[i] : ((const float4*)ie)[i - usplit];
        ushort4 o;
        o.x = f32_to_bf16(f.x);
        o.y = f32_to_bf16(f.y);
        o.z = f32_to_bf16(f.z);
        o.w = f32_to_bf16(f.w);
        ((ushort4*)xb)[i] = o;
        return;
    }

    // ---- binning ----
    __shared__ int  ccnt[NBP];
    __shared__ int  cpos[NBP];
    __shared__ int  gdst[NBP];
    __shared__ int2 entries[BIN_CHUNK];            // 16 KB
    __shared__ ushort_t ebuck[BIN_CHUNK];          // 4 KB

    int base = (blockIdx.x - g_conv) * BIN_CHUNK;
    ccnt[t] = 0;
    __syncthreads();

    int myrow[BIN_CHUNK / 512];
#pragma unroll
    for (int k = 0; k < BIN_CHUNK / 512; k++) {
        int idx = base + k * 512 + t;
        int r = (idx < nnz) ? rows[idx] : -1;
        myrow[k] = r;
        if (r >= 0) {
            atomicAdd(&ccnt[r >> ROW_SHIFT], 1);
            atomicAdd(&rc[r], 1);                  // per-row count (R18)
        }
    }
    __syncthreads();

    int c = ccnt[t];
    cpos[t] = c;
    __syncthreads();
    for (int d = 1; d < NBP; d <<= 1) {
        int y = (t >= d) ? cpos[t - d] : 0;
        __syncthreads();
        cpos[t] += y;
        __syncthreads();
    }
    int total = cpos[NBP - 1];
    int excl = cpos[t] - c;
    __syncthreads();
    cpos[t] = excl;
    __syncthreads();

#pragma unroll
    for (int k = 0; k < BIN_CHUNK / 512; k++) {
        int r = myrow[k];
        if (r >= 0) {
            int idx = base + k * 512 + t;
            int b = r >> ROW_SHIFT;
            int lrow = r & (ROWS_PER_BUCKET - 1);
            int slot = atomicAdd(&cpos[b], 1);
            entries[slot] = make_int2(cols[idx] | (lrow << 18), __float_as_int(vals[idx]));
            ebuck[slot] = (ushort_t)b;
        }
    }
    __syncthreads();

    // reserve space in each touched bucket's fixed region
    if (t < B_BUCKETS && ccnt[t] > 0) {
        int g = atomicAdd(&cursor[t], ccnt[t]);
        gdst[t] = t * cap + g - (cpos[t] - ccnt[t]);   // minus local run base
    }
    __syncthreads();

    for (int i = t; i < total; i += 512) {
        int eb = ebuck[i];
        int pos = gdst[eb] + i;
        if (pos < (eb + 1) * cap)                     // capacity guard (never hits)
            staging[pos] = entries[i];
    }
}

// ---------------------------------------------------------------------------
// k_scanb: one block per bucket (512 rows). Exclusive scan of rc within the
// bucket -> per-row ranges {beg,end} and the place-cursor cur[row]=beg.
// cv keeps the per-bucket padded layout (bucket b starts at b*cap), which
// preserves k_spmm's tail-overread slack (cap has 16-sigma margin).
// ---------------------------------------------------------------------------
__global__ void __launch_bounds__(512) k_scanb(const int* __restrict__ rc,
                                               int2* __restrict__ ranges,
                                               int* __restrict__ cur, int cap) {
    __shared__ int sc[ROWS_PER_BUCKET];
    int b = blockIdx.x;
    int t = threadIdx.x;
    int row = (b << ROW_SHIFT) + t;
    int c = (row < N_NODES) ? rc[row] : 0;
    sc[t] = c;
    __syncthreads();
    for (int d = 1; d < ROWS_PER_BUCKET; d <<= 1) {
        int y = (t >= d) ? sc[t - d] : 0;
        __syncthreads();
        sc[t] += y;
        __syncthreads();
    }
    int excl = sc[t] - c;
    int beg = b * cap + excl;
    if (row < N_NODES) {
        ranges[row] = make_int2(beg, beg + c);
        cur[row] = beg;
    }
}

// ---------------------------------------------------------------------------
// k_rplace: full-occupancy within-bucket placement, replacing the
// 293-block k_scatter2b (2.3 waves/SIMD, two staging passes, LDS scan).
// Grid = B_BUCKETS x chunks; block (b,k) reads PLACE_CHUNK staging entries
// of bucket b coalesced and scatters them to their row-sorted cv positions
// via cur[] atomics. All writes land inside bucket b's ~131 KB region ->
// L2-merged, written once (unlike R17's full-range scatter, 8x write amp).
// Within-row order nondeterministic (same class as old scheme).
// pos is bounded by construction: cur starts at beg, each row receives
// exactly rc[row] entries, and the bucket scan total <= cnt_b <= cap.
// ---------------------------------------------------------------------------
__global__ void __launch_bounds__(512) k_rplace(const int2* __restrict__ staging,
                                                const int* __restrict__ cursor,
                                                int* __restrict__ cur,
                                                int2* __restrict__ cv,
                                                int cap, int chunks) {
    int b = blockIdx.x / chunks;
    int k = blockIdx.x - b * chunks;
    int cnt_b = cursor[b];
    if (cnt_b > cap) cnt_b = cap;
    int lo = k * PLACE_CHUNK;
    int hi = lo + PLACE_CHUNK;
    if (hi > cnt_b) hi = cnt_b;
    int row0 = b << ROW_SHIFT;
    int rbase = b * cap;
#pragma unroll 1
    for (int i = lo + (int)threadIdx.x; i < hi; i += 512) {
        int2 e = staging[rbase + i];
        int lrow = e.x >> 18;
        int pos = atomicAdd(&cur[row0 + lrow], 1);
        cv[pos] = make_int2(e.x & COL_MASK, e.y);
    }
}

// ---------------------------------------------------------------------------
// R16 readlane-broadcast SpMM row body (UNCHANGED — verified 87.5 us).
// Edge stream: lane l loads edge beg+l with ONE coalesced global_load_dwordx2
// (64 edges / 512B / one vmcnt entry). Invalid lanes clamp col->0 / val->0
// (row 0 stays L1-hot, contributes 0; also shields uninitialized cv slack).
// Each edge broadcast via v_readlane; gathers issue in a 32-wide window then
// drain in-order. Overreads stay inside the bucket's padded slack.
// ---------------------------------------------------------------------------
#define ISSUE8(R, J0)                                                         \
    _Pragma("unroll")                                                         \
    for (int j = 0; j < 8; j++) {                                             \
        int sc = __builtin_amdgcn_readlane(vc, (J0) + j);                     \
        R[j] = xb[((size_t)(uint_t)sc << 6) + lane];                          \
    }

#define CONS8(R, J0)                                                          \
    _Pragma("unroll")                                                         \
    for (int j = 0; j < 8; j++) {                                             \
        float sv = __uint_as_float((uint_t)__builtin_amdgcn_readlane(vv, (J0) + j)); \
        acc += sv * __uint_as_float((uint_t)R[j] << 16);                      \
    }

__device__ __forceinline__ float spmm_row_rl(int beg, int end, int lane,
                                             const int2* __restrict__ cv,
                                             const ushort_t* __restrict__ xb) {
    float acc = 0.f;
#pragma unroll 1
    for (int b = beg; b < end; b += 64) {
        int2 ed = cv[b + lane];              // coalesced 512B, 1 vmcnt entry
        bool lv = (b + lane) < end;
        int vc = lv ? ed.x : 0;              // per-lane clamp (2 cndmask)
        int vv = lv ? ed.y : 0;
        int rem = end - b;                   // wave-uniform
        if (rem > 64) rem = 64;

        ushort_t q0[8], q1[8], q2[8], q3[8];
        // ---- half 0: edges 0..31 ----
        ISSUE8(q0, 0)
        if (rem > 8)  { ISSUE8(q1, 8)  }
        if (rem > 16) { ISSUE8(q2, 16) }
        if (rem > 24) { ISSUE8(q3, 24) }
        CONS8(q0, 0)
        if (rem > 8)  { CONS8(q1, 8)  }
        if (rem > 16) { CONS8(q2, 16) }
        if (rem > 24) { CONS8(q3, 24) }
        // ---- half 1: edges 32..63 ----
        if (rem > 32) {
            ISSUE8(q0, 32)
            if (rem > 40) { ISSUE8(q1, 40) }
            if (rem > 48) { ISSUE8(q2, 48) }
            if (rem > 56) { ISSUE8(q3, 56) }
            CONS8(q0, 32)
            if (rem > 40) { CONS8(q1, 40) }
            if (rem > 48) { CONS8(q2, 48) }
            if (rem > 56) { CONS8(q3, 56) }
        }
    }
    return acc;
}

__global__ void k_spmm(const int2* __restrict__ ranges, const int2* __restrict__ cv,
                       const ushort_t* __restrict__ xb, ushort_t* __restrict__ out) {
    int row = (blockIdx.x * blockDim.x + threadIdx.x) >> 6;
    int lane = threadIdx.x & 63;
    if (row >= N_NODES) return;
    row = __builtin_amdgcn_readfirstlane(row);
    int2 rng = ranges[row];
    int beg = __builtin_amdgcn_readfirstlane(rng.x);
    int end = __builtin_amdgcn_readfirstlane(rng.y);
    float a = spmm_row_rl(beg, end, lane, cv, xb);
    out[(size_t)row * 64 + lane] = f32_to_bf16(a);   // 64 lanes x 2B = 128B
}

// ---------------------------------------------------------------------------
// k_last (UNCHANGED): one wave per batch element. Layer-3 rows for BOTH the
// user node and item node, gathers ego(fp32)+xbA+xbB, emits the dot.
// ---------------------------------------------------------------------------
__global__ void k_last(const int2* __restrict__ ranges, const int2* __restrict__ cv,
                       const int* __restrict__ users, const int* __restrict__ items,
                       const float* __restrict__ ue, const float* __restrict__ ie,
                       const ushort_t* __restrict__ xbA, const ushort_t* __restrict__ xbB,
                       float* __restrict__ out, int batch) {
    int w = (blockIdx.x * blockDim.x + threadIdx.x) >> 6;
    int lane = threadIdx.x & 63;
    if (w >= batch) return;

    int uu = __builtin_amdgcn_readfirstlane(users[w]);
    int ii = __builtin_amdgcn_readfirstlane(items[w]);
    int row_u = uu;
    int row_i = NUM_USERS + ii;

    // layer-3 contributions (source = xbB)
    int2 ru = ranges[row_u];
    float a_u = spmm_row_rl(__builtin_amdgcn_readfirstlane(ru.x),
                            __builtin_amdgcn_readfirstlane(ru.y), lane, cv, xbB);
    int2 ri = ranges[row_i];
    float a_i = spmm_row_rl(__builtin_amdgcn_readfirstlane(ri.x),
                            __builtin_amdgcn_readfirstlane(ri.y), lane, cv, xbB);

    float e_u = ue[(size_t)uu * EMBED_DIM + lane];
    float e_i = ie[(size_t)ii * EMBED_DIM + lane];
    float Au = bf16_to_f32(xbA[(size_t)row_u * 64 + lane]);
    float Bu = bf16_to_f32(xbB[(size_t)row_u * 64 + lane]);
    float Ai = bf16_to_f32(xbA[(size_t)row_i * 64 + lane]);
    float Bi = bf16_to_f32(xbB[(size_t)row_i * 64 + lane]);

    float ux = e_u + Au + Bu + a_u;
    float ix = e_i + Ai + Bi + a_i;

    float p = ux * ix;
#pragma unroll
    for (int d = 32; d > 0; d >>= 1) p += __shfl_down(p, d, 64);
    if (lane == 0) out[w] = p * (1.0f / 16.0f);   // 1/16 mean^2 scale
}

// ---------------------------------------------------------------------------

extern "C" void kernel_launch(void* const* d_in, const int* in_sizes, int n_in,
                              void* d_out, int out_size, void* d_ws, size_t ws_size,
                              hipStream_t stream) {
    const int*   users    = (const int*)  d_in[0];
    const int*   items    = (const int*)  d_in[1];
    const int*   adj_rows = (const int*)  d_in[2];
    const int*   adj_cols = (const int*)  d_in[3];
    const float* adj_vals = (const float*)d_in[4];
    const float* user_emb = (const float*)d_in[5];
    const float* item_emb = (const float*)d_in[6];
    float* out = (float*)d_out;

    const int batch = in_sizes[0];
    const int nnz   = in_sizes[2];

    // fixed bucket capacity: mean * 9/8, rounded up to 64 (16-sigma margin)
    int cap = ((nnz / B_BUCKETS) * 9 + 7) / 8;
    cap = (cap + 63) & ~63;
    const size_t padded = (size_t)B_BUCKETS * cap;   // ~5.4M entries

    char* p = (char*)d_ws;
    auto alloc = [&](size_t bytes) -> char* {
        char* r = p;
        p += (bytes + 255) & ~(size_t)255;
        return r;
    };
    const size_t xb_bytes = (size_t)N_NODES * EMBED_DIM * 2;       // 19.2 MB
    int2*     ranges = (int2*) alloc((size_t)N_NODES * 8);
    int*      cursor = (int*)  alloc((NBP + 2 * (size_t)N_NODES) * 4);  // + rc + cur
    int*      rc     = cursor + NBP;
    int*      cur    = rc + N_NODES;
    int2*     cv     = (int2*) alloc(padded * 8);                  // padded CSR
    // region overlays: staging (build) vs xbA+xbB (layer buffers)
    size_t    region_bytes = padded * 8;
    if (region_bytes < 2 * xb_bytes) region_bytes = 2 * xb_bytes;
    char*     region  = alloc(region_bytes);
    int2*     staging = (int2*)region;
    ushort_t* xbA     = (ushort_t*)region;
    ushort_t* xbB     = (ushort_t*)(region + xb_bytes);
    ushort_t* xb_ego  = (ushort_t*)alloc(xb_bytes);

    const int g_conv  = ((N_NODES * EMBED_DIM / 4) + 511) / 512;   // 4688
    const int g_bin   = (nnz + BIN_CHUNK - 1) / BIN_CHUNK;         // 2344
    const int chunks  = (cap + PLACE_CHUNK - 1) / PLACE_CHUNK;     // ~9
    const int g_nodes = (N_NODES + 3) / 4;                         // 4 waves/block
    const int g_batch = (batch + 3) / 4;

    // ---- build: bin(+rowcount) -> bucket-scan -> within-bucket place ----
    hipMemsetAsync(cursor, 0, (NBP + (size_t)N_NODES) * 4, stream);  // cursor+rc
    k_bin2<<<g_conv + g_bin, 512, 0, stream>>>(user_emb, item_emb, xb_ego,
                                               adj_rows, adj_cols, adj_vals,
                                               cursor, rc, staging, nnz, cap, g_conv);
    k_scanb<<<B_BUCKETS, 512, 0, stream>>>(rc, ranges, cur, cap);
    k_rplace<<<B_BUCKETS * chunks, 512, 0, stream>>>(staging, cursor, cur, cv,
                                                     cap, chunks);

    // ---- layer 1: xbA = A * ego ----
    k_spmm<<<g_nodes, 256, 0, stream>>>(ranges, cv, xb_ego, xbA);

    // ---- layer 2: xbB = A * xbA ----
    k_spmm<<<g_nodes, 256, 0, stream>>>(ranges, cv, xbA, xbB);

    // ---- layer 3 (batch rows only) + gather + dot, fused ----
    k_last<<<g_batch, 256, 0, stream>>>(ranges, cv, users, items,
                                        user_emb, item_emb, xbA, xbB, out, batch);
}

// Round 8
// 425.748 us; speedup vs baseline: 1.8078x; 1.6273x over previous
//
#include <hip/hip_runtime.h>
#include <hip/hip_bf16.h>

#define NUM_USERS 100000
#define NUM_ITEMS 50000
#define EMBED_DIM 64
#define N_NODES   150000                 // NUM_USERS + NUM_ITEMS
#define ROW_SHIFT 9                      // 512 rows per bucket
#define ROWS_PER_BUCKET 512
#define B_BUCKETS ((N_NODES + ROWS_PER_BUCKET - 1) / ROWS_PER_BUCKET)   // 293
#define NBP 512                          // padded bucket-array size
#define BIN_CHUNK 2048                   // edges per bin block (4/thread @512)
#define PLACE_CHUNK 2048                 // staging entries per hist/place block
#define COL_MASK 0x3FFFF                 // 18 bits for col (N_NODES < 262144)

typedef unsigned short ushort_t;
typedef unsigned int uint_t;

__device__ __forceinline__ float bf16_to_f32(ushort_t u) {
    return __uint_as_float(((unsigned)u) << 16);
}
__device__ __forceinline__ ushort_t f32_to_bf16(float f) {
    return __builtin_bit_cast(ushort_t, __float2bfloat16(f));   // RNE
}

// ---------------------------------------------------------------------------
// k_bin2 (EXACT R16 revert — LDS-only atomics). Heterogeneous grid: first
// g_conv blocks convert fp32 ego -> bf16; the rest LDS-bin edges into
// FIXED-CAPACITY bucket regions of `staging`. The LDS compaction keeps
// staging writes bucket-run-contiguous (low write amplification — R17's
// direct scatter hit 8x amp). R18 LESSON: per-edge GLOBAL atomics (rc[])
// cost ~35 ns/op effective (243 us, 165 MB of coherence write traffic) —
// never on the edge-hot path. Staging entry: int2 {col | lrow<<18, val}.
// ---------------------------------------------------------------------------
__global__ void __launch_bounds__(512) k_bin2(const float* __restrict__ ue,
                                              const float* __restrict__ ie,
                                              ushort_t* __restrict__ xb,
                                              const int* __restrict__ rows,
                                              const int* __restrict__ cols,
                                              const float* __restrict__ vals,
                                              int* __restrict__ cursor,
                                              int2* __restrict__ staging,
                                              int nnz, int cap, int g_conv) {
    int t = threadIdx.x;
    if ((int)blockIdx.x < g_conv) {
        // ---- convert: fp32 ego table -> bf16 (float4 granularity) ----
        int i = blockIdx.x * 512 + t;
        const int n4 = (N_NODES * EMBED_DIM) / 4;
        if (i >= n4) return;
        const int usplit = (NUM_USERS * EMBED_DIM) / 4;
        float4 f = (i < usplit) ? ((const float4*)ue)[i] : ((const float4*)ie)[i - usplit];
        ushort4 o;
        o.x = f32_to_bf16(f.x);
        o.y = f32_to_bf16(f.y);
        o.z = f32_to_bf16(f.z);
        o.w = f32_to_bf16(f.w);
        ((ushort4*)xb)[i] = o;
        return;
    }

    // ---- binning ----
    __shared__ int  ccnt[NBP];
    __shared__ int  cpos[NBP];
    __shared__ int  gdst[NBP];
    __shared__ int2 entries[BIN_CHUNK];            // 16 KB
    __shared__ ushort_t ebuck[BIN_CHUNK];          // 4 KB

    int base = (blockIdx.x - g_conv) * BIN_CHUNK;
    ccnt[t] = 0;
    __syncthreads();

    int myrow[BIN_CHUNK / 512];
#pragma unroll
    for (int k = 0; k < BIN_CHUNK / 512; k++) {
        int idx = base + k * 512 + t;
        int r = (idx < nnz) ? rows[idx] : -1;
        myrow[k] = r;
        if (r >= 0) atomicAdd(&ccnt[r >> ROW_SHIFT], 1);
    }
    __syncthreads();

    int c = ccnt[t];
    cpos[t] = c;
    __syncthreads();
    for (int d = 1; d < NBP; d <<= 1) {
        int y = (t >= d) ? cpos[t - d] : 0;
        __syncthreads();
        cpos[t] += y;
        __syncthreads();
    }
    int total = cpos[NBP - 1];
    int excl = cpos[t] - c;
    __syncthreads();
    cpos[t] = excl;
    __syncthreads();

#pragma unroll
    for (int k = 0; k < BIN_CHUNK / 512; k++) {
        int r = myrow[k];
        if (r >= 0) {
            int idx = base + k * 512 + t;
            int b = r >> ROW_SHIFT;
            int lrow = r & (ROWS_PER_BUCKET - 1);
            int slot = atomicAdd(&cpos[b], 1);
            entries[slot] = make_int2(cols[idx] | (lrow << 18), __float_as_int(vals[idx]));
            ebuck[slot] = (ushort_t)b;
        }
    }
    __syncthreads();

    // reserve space in each touched bucket's fixed region
    if (t < B_BUCKETS && ccnt[t] > 0) {
        int g = atomicAdd(&cursor[t], ccnt[t]);
        gdst[t] = t * cap + g - (cpos[t] - ccnt[t]);   // minus local run base
    }
    __syncthreads();

    for (int i = t; i < total; i += 512) {
        int eb = ebuck[i];
        int pos = gdst[eb] + i;
        if (pos < (eb + 1) * cap)                     // capacity guard (never hits)
            staging[pos] = entries[i];
    }
}

// ---------------------------------------------------------------------------
// k_hist: full-occupancy per-(bucket,chunk) row histogram. Block (b,k) reads
// its PLACE_CHUNK staging entries coalesced, histograms local rows in LDS,
// and writes the 512-int histogram to its PRIVATE slot H[b][k][.] — no
// global atomics anywhere. Replaces pass 1 of the old 293-block k_scatter2b.
// ---------------------------------------------------------------------------
__global__ void __launch_bounds__(512) k_hist(const int2* __restrict__ staging,
                                              const int* __restrict__ cursor,
                                              int* __restrict__ H,
                                              int cap, int chunks) {
    __shared__ int h[ROWS_PER_BUCKET];
    int b = blockIdx.x / chunks;
    int k = blockIdx.x - b * chunks;
    int t = threadIdx.x;
    h[t] = 0;
    __syncthreads();
    int cnt_b = cursor[b];
    if (cnt_b > cap) cnt_b = cap;
    int hi = k * PLACE_CHUNK + PLACE_CHUNK;
    if (hi > cnt_b) hi = cnt_b;
    int rbase = b * cap;
#pragma unroll 1
    for (int i = k * PLACE_CHUNK + t; i < hi; i += 512)
        atomicAdd(&h[staging[rbase + i].x >> 18], 1);
    __syncthreads();
    H[(size_t)blockIdx.x * ROWS_PER_BUCKET + t] = h[t];
}

// ---------------------------------------------------------------------------
// k_scan2: one block per bucket, but touches only chunks*2KB of H (18 KB) —
// NOT the 2x38.4MB staging re-read that made old k_scatter2b ~85 us at 2
// waves/SIMD. Thread t owns row t: rc = sum_k H[b][k][t] (coalesced per k),
// bucket-wide exclusive scan -> ranges; then rewrites H[b][k][t] to the
// per-(chunk,row) start cursor (prefix across chunks).
// ---------------------------------------------------------------------------
__global__ void __launch_bounds__(512) k_scan2(int* __restrict__ H,
                                               int2* __restrict__ ranges,
                                               int cap, int chunks) {
    __shared__ int sc[ROWS_PER_BUCKET];
    int b = blockIdx.x;
    int t = threadIdx.x;
    size_t base = (size_t)b * chunks * ROWS_PER_BUCKET + t;
    int c = 0;
#pragma unroll 1
    for (int k = 0; k < chunks; k++) c += H[base + (size_t)k * ROWS_PER_BUCKET];
    sc[t] = c;
    __syncthreads();
    for (int d = 1; d < ROWS_PER_BUCKET; d <<= 1) {
        int y = (t >= d) ? sc[t - d] : 0;
        __syncthreads();
        sc[t] += y;
        __syncthreads();
    }
    int excl = sc[t] - c;
    int row = (b << ROW_SHIFT) + t;
    int beg = b * cap + excl;
    if (row < N_NODES) ranges[row] = make_int2(beg, beg + c);
    int s = beg;
#pragma unroll 1
    for (int k = 0; k < chunks; k++) {
        int hh = H[base + (size_t)k * ROWS_PER_BUCKET];
        H[base + (size_t)k * ROWS_PER_BUCKET] = s;
        s += hh;
    }
}

// ---------------------------------------------------------------------------
// k_place2: full-occupancy placement. Block (b,k) loads its per-(chunk,row)
// start cursors into LDS, re-reads its staging chunk coalesced, and places
// each entry at pos = ldsAtomicAdd(&c[lrow],1). LDS atomics only; every
// (b,k,row) slice receives exactly h[b][k][row] entries -> pos bounded by
// the bucket region by construction. Writes confined to the bucket's
// ~147 KB cv window -> L2-merged, written once (R17's full-range scatter
// had 8x write amp; R18's cur[] variant paid 4.8M global atomics).
// ---------------------------------------------------------------------------
__global__ void __launch_bounds__(512) k_place2(const int2* __restrict__ staging,
                                                const int* __restrict__ cursor,
                                                const int* __restrict__ H,
                                                int2* __restrict__ cv,
                                                int cap, int chunks) {
    __shared__ int c[ROWS_PER_BUCKET];
    int b = blockIdx.x / chunks;
    int k = blockIdx.x - b * chunks;
    int t = threadIdx.x;
    c[t] = H[(size_t)blockIdx.x * ROWS_PER_BUCKET + t];
    __syncthreads();
    int cnt_b = cursor[b];
    if (cnt_b > cap) cnt_b = cap;
    int hi = k * PLACE_CHUNK + PLACE_CHUNK;
    if (hi > cnt_b) hi = cnt_b;
    int rbase = b * cap;
#pragma unroll 1
    for (int i = k * PLACE_CHUNK + t; i < hi; i += 512) {
        int2 e = staging[rbase + i];
        int pos = atomicAdd(&c[e.x >> 18], 1);
        cv[pos] = make_int2(e.x & COL_MASK, e.y);
    }
}

// ---------------------------------------------------------------------------
// R16 readlane-broadcast SpMM row body (UNCHANGED — verified 87.5 us).
// Edge stream: lane l loads edge beg+l with ONE coalesced global_load_dwordx2
// (64 edges / 512B / one vmcnt entry). Invalid lanes clamp col->0 / val->0
// (row 0 stays L1-hot, contributes 0; also shields uninitialized cv slack).
// Each edge broadcast via v_readlane; gathers issue in a 32-wide window then
// drain in-order. Overreads stay inside the bucket's padded slack.
// ---------------------------------------------------------------------------
#define ISSUE8(R, J0)                                                         \
    _Pragma("unroll")                                                         \
    for (int j = 0; j < 8; j++) {                                             \
        int sc = __builtin_amdgcn_readlane(vc, (J0) + j);                     \
        R[j] = xb[((size_t)(uint_t)sc << 6) + lane];                          \
    }

#define CONS8(R, J0)                                                          \
    _Pragma("unroll")                                                         \
    for (int j = 0; j < 8; j++) {                                             \
        float sv = __uint_as_float((uint_t)__builtin_amdgcn_readlane(vv, (J0) + j)); \
        acc += sv * __uint_as_float((uint_t)R[j] << 16);                      \
    }

__device__ __forceinline__ float spmm_row_rl(int beg, int end, int lane,
                                             const int2* __restrict__ cv,
                                             const ushort_t* __restrict__ xb) {
    float acc = 0.f;
#pragma unroll 1
    for (int b = beg; b < end; b += 64) {
        int2 ed = cv[b + lane];              // coalesced 512B, 1 vmcnt entry
        bool lv = (b + lane) < end;
        int vc = lv ? ed.x : 0;              // per-lane clamp (2 cndmask)
        int vv = lv ? ed.y : 0;
        int rem = end - b;                   // wave-uniform
        if (rem > 64) rem = 64;

        ushort_t q0[8], q1[8], q2[8], q3[8];
        // ---- half 0: edges 0..31 ----
        ISSUE8(q0, 0)
        if (rem > 8)  { ISSUE8(q1, 8)  }
        if (rem > 16) { ISSUE8(q2, 16) }
        if (rem > 24) { ISSUE8(q3, 24) }
        CONS8(q0, 0)
        if (rem > 8)  { CONS8(q1, 8)  }
        if (rem > 16) { CONS8(q2, 16) }
        if (rem > 24) { CONS8(q3, 24) }
        // ---- half 1: edges 32..63 ----
        if (rem > 32) {
            ISSUE8(q0, 32)
            if (rem > 40) { ISSUE8(q1, 40) }
            if (rem > 48) { ISSUE8(q2, 48) }
            if (rem > 56) { ISSUE8(q3, 56) }
            CONS8(q0, 32)
            if (rem > 40) { CONS8(q1, 40) }
            if (rem > 48) { CONS8(q2, 48) }
            if (rem > 56) { CONS8(q3, 56) }
        }
    }
    return acc;
}

__global__ void k_spmm(const int2* __restrict__ ranges, const int2* __restrict__ cv,
                       const ushort_t* __restrict__ xb, ushort_t* __restrict__ out) {
    int row = (blockIdx.x * blockDim.x + threadIdx.x) >> 6;
    int lane = threadIdx.x & 63;
    if (row >= N_NODES) return;
    row = __builtin_amdgcn_readfirstlane(row);
    int2 rng = ranges[row];
    int beg = __builtin_amdgcn_readfirstlane(rng.x);
    int end = __builtin_amdgcn_readfirstlane(rng.y);
    float a = spmm_row_rl(beg, end, lane, cv, xb);
    out[(size_t)row * 64 + lane] = f32_to_bf16(a);   // 64 lanes x 2B = 128B
}

// ---------------------------------------------------------------------------
// k_last (UNCHANGED): one wave per batch element. Layer-3 rows for BOTH the
// user node and item node, gathers ego(fp32)+xbA+xbB, emits the dot.
// ---------------------------------------------------------------------------
__global__ void k_last(const int2* __restrict__ ranges, const int2* __restrict__ cv,
                       const int* __restrict__ users, const int* __restrict__ items,
                       const float* __restrict__ ue, const float* __restrict__ ie,
                       const ushort_t* __restrict__ xbA, const ushort_t* __restrict__ xbB,
                       float* __restrict__ out, int batch) {
    int w = (blockIdx.x * blockDim.x + threadIdx.x) >> 6;
    int lane = threadIdx.x & 63;
    if (w >= batch) return;

    int uu = __builtin_amdgcn_readfirstlane(users[w]);
    int ii = __builtin_amdgcn_readfirstlane(items[w]);
    int row_u = uu;
    int row_i = NUM_USERS + ii;

    // layer-3 contributions (source = xbB)
    int2 ru = ranges[row_u];
    float a_u = spmm_row_rl(__builtin_amdgcn_readfirstlane(ru.x),
                            __builtin_amdgcn_readfirstlane(ru.y), lane, cv, xbB);
    int2 ri = ranges[row_i];
    float a_i = spmm_row_rl(__builtin_amdgcn_readfirstlane(ri.x),
                            __builtin_amdgcn_readfirstlane(ri.y), lane, cv, xbB);

    float e_u = ue[(size_t)uu * EMBED_DIM + lane];
    float e_i = ie[(size_t)ii * EMBED_DIM + lane];
    float Au = bf16_to_f32(xbA[(size_t)row_u * 64 + lane]);
    float Bu = bf16_to_f32(xbB[(size_t)row_u * 64 + lane]);
    float Ai = bf16_to_f32(xbA[(size_t)row_i * 64 + lane]);
    float Bi = bf16_to_f32(xbB[(size_t)row_i * 64 + lane]);

    float ux = e_u + Au + Bu + a_u;
    float ix = e_i + Ai + Bi + a_i;

    float p = ux * ix;
#pragma unroll
    for (int d = 32; d > 0; d >>= 1) p += __shfl_down(p, d, 64);
    if (lane == 0) out[w] = p * (1.0f / 16.0f);   // 1/16 mean^2 scale
}

// ---------------------------------------------------------------------------

extern "C" void kernel_launch(void* const* d_in, const int* in_sizes, int n_in,
                              void* d_out, int out_size, void* d_ws, size_t ws_size,
                              hipStream_t stream) {
    const int*   users    = (const int*)  d_in[0];
    const int*   items    = (const int*)  d_in[1];
    const int*   adj_rows = (const int*)  d_in[2];
    const int*   adj_cols = (const int*)  d_in[3];
    const float* adj_vals = (const float*)d_in[4];
    const float* user_emb = (const float*)d_in[5];
    const float* item_emb = (const float*)d_in[6];
    float* out = (float*)d_out;

    const int batch = in_sizes[0];
    const int nnz   = in_sizes[2];

    // fixed bucket capacity: mean * 9/8, rounded up to 64 (16-sigma margin)
    int cap = ((nnz / B_BUCKETS) * 9 + 7) / 8;
    cap = (cap + 63) & ~63;
    const size_t padded = (size_t)B_BUCKETS * cap;   // ~5.4M entries
    const int chunks = (cap + PLACE_CHUNK - 1) / PLACE_CHUNK;     // ~9

    char* p = (char*)d_ws;
    auto alloc = [&](size_t bytes) -> char* {
        char* r = p;
        p += (bytes + 255) & ~(size_t)255;
        return r;
    };
    const size_t xb_bytes = (size_t)N_NODES * EMBED_DIM * 2;       // 19.2 MB
    int2*     ranges = (int2*) alloc((size_t)N_NODES * 8);
    int*      cursor = (int*)  alloc(NBP * 4);
    int*      H      = (int*)  alloc((size_t)B_BUCKETS * chunks * ROWS_PER_BUCKET * 4); // 5.4 MB
    int2*     cv     = (int2*) alloc(padded * 8);                  // padded CSR
    // region overlays: staging (build) vs xbA+xbB (layer buffers)
    size_t    region_bytes = padded * 8;
    if (region_bytes < 2 * xb_bytes) region_bytes = 2 * xb_bytes;
    char*     region  = alloc(region_bytes);
    int2*     staging = (int2*)region;
    ushort_t* xbA     = (ushort_t*)region;
    ushort_t* xbB     = (ushort_t*)(region + xb_bytes);
    ushort_t* xb_ego  = (ushort_t*)alloc(xb_bytes);

    const int g_conv  = ((N_NODES * EMBED_DIM / 4) + 511) / 512;   // 4688
    const int g_bin   = (nnz + BIN_CHUNK - 1) / BIN_CHUNK;         // 2344
    const int g_nodes = (N_NODES + 3) / 4;                         // 4 waves/block
    const int g_batch = (batch + 3) / 4;

    // ---- build: bin -> per-chunk hist -> scan -> place (no global atomics
    // on the edge-hot path anywhere) ----
    hipMemsetAsync(cursor, 0, NBP * 4, stream);
    k_bin2<<<g_conv + g_bin, 512, 0, stream>>>(user_emb, item_emb, xb_ego,
                                               adj_rows, adj_cols, adj_vals,
                                               cursor, staging, nnz, cap, g_conv);
    k_hist<<<B_BUCKETS * chunks, 512, 0, stream>>>(staging, cursor, H, cap, chunks);
    k_scan2<<<B_BUCKETS, 512, 0, stream>>>(H, ranges, cap, chunks);
    k_place2<<<B_BUCKETS * chunks, 512, 0, stream>>>(staging, cursor, H, cv,
                                                     cap, chunks);

    // ---- layer 1: xbA = A * ego ----
    k_spmm<<<g_nodes, 256, 0, stream>>>(ranges, cv, xb_ego, xbA);

    // ---- layer 2: xbB = A * xbA ----
    k_spmm<<<g_nodes, 256, 0, stream>>>(ranges, cv, xbA, xbB);

    // ---- layer 3 (batch rows only) + gather + dot, fused ----
    k_last<<<g_batch, 256, 0, stream>>>(ranges, cv, users, items,
                                        user_emb, item_emb, xbA, xbB, out, batch);
}

// Round 9
// 422.458 us; speedup vs baseline: 1.8219x; 1.0078x over previous
//
#include <hip/hip_runtime.h>
#include <hip/hip_bf16.h>

#define NUM_USERS 100000
#define NUM_ITEMS 50000
#define EMBED_DIM 64
#define N_NODES   150000                 // NUM_USERS + NUM_ITEMS
#define ROW_SHIFT 9                      // 512 rows per bucket
#define ROWS_PER_BUCKET 512
#define B_BUCKETS ((N_NODES + ROWS_PER_BUCKET - 1) / ROWS_PER_BUCKET)   // 293
#define NBP 512                          // padded bucket-array size
#define BIN_CHUNK 2048                   // edges per bin block (4/thread @512)
#define PLACE_CHUNK 2048                 // staging entries per hist/place block
#define COL_MASK 0x3FFFF                 // 18 bits for col (N_NODES < 262144)

typedef unsigned short ushort_t;
typedef unsigned int uint_t;

__device__ __forceinline__ float bf16_to_f32(ushort_t u) {
    return __uint_as_float(((unsigned)u) << 16);
}
__device__ __forceinline__ ushort_t f32_to_bf16(float f) {
    return __builtin_bit_cast(ushort_t, __float2bfloat16(f));   // RNE
}

// 512-thread (8-wave) exclusive scan via shfl_up: 2 barriers instead of 18.
// Writes excl to *excl_out, returns total via *total_out (valid after call).
// wsum must be an 8-int LDS array.
__device__ __forceinline__ void scan512(int c, int t, int* wsum,
                                        int* excl_out, int* total_out) {
    int lane = t & 63, wv = t >> 6;
    int x = c;
#pragma unroll
    for (int d = 1; d < 64; d <<= 1) {
        int y = __shfl_up(x, d, 64);
        if (lane >= d) x += y;
    }
    if (lane == 63) wsum[wv] = x;
    __syncthreads();
    if (t < 64) {
        int s = (lane < 8) ? wsum[lane] : 0;
#pragma unroll
        for (int d = 1; d < 8; d <<= 1) {
            int y = __shfl_up(s, d, 64);
            if (lane >= d) s += y;
        }
        if (lane < 8) wsum[lane] = s;
    }
    __syncthreads();
    int off = (wv > 0) ? wsum[wv - 1] : 0;
    *excl_out = x + off - c;
    *total_out = wsum[7];
}

// ---------------------------------------------------------------------------
// k_bin2 (R20): LDS-only atomics; heterogeneous grid (convert + bin).
// Changes vs verified R16 body: (a) 18-barrier Hillis-Steele scan replaced
// by 2-barrier shfl scan; (b) cols/vals loaded into registers in pass 1
// (no second global fetch of the edge arrays). Semantics identical.
// R18 LESSON kept: no per-edge global atomics anywhere.
// ---------------------------------------------------------------------------
__global__ void __launch_bounds__(512) k_bin2(const float* __restrict__ ue,
                                              const float* __restrict__ ie,
                                              ushort_t* __restrict__ xb,
                                              const int* __restrict__ rows,
                                              const int* __restrict__ cols,
                                              const float* __restrict__ vals,
                                              int* __restrict__ cursor,
                                              int2* __restrict__ staging,
                                              int nnz, int cap, int g_conv) {
    int t = threadIdx.x;
    if ((int)blockIdx.x < g_conv) {
        // ---- convert: fp32 ego table -> bf16 (float4 granularity) ----
        int i = blockIdx.x * 512 + t;
        const int n4 = (N_NODES * EMBED_DIM) / 4;
        if (i >= n4) return;
        const int usplit = (NUM_USERS * EMBED_DIM) / 4;
        float4 f = (i < usplit) ? ((const float4*)ue)[i] : ((const float4*)ie)[i - usplit];
        ushort4 o;
        o.x = f32_to_bf16(f.x);
        o.y = f32_to_bf16(f.y);
        o.z = f32_to_bf16(f.z);
        o.w = f32_to_bf16(f.w);
        ((ushort4*)xb)[i] = o;
        return;
    }

    // ---- binning ----
    __shared__ int  ccnt[NBP];
    __shared__ int  cpos[NBP];
    __shared__ int  gdst[NBP];
    __shared__ int  wsum[8];
    __shared__ int2 entries[BIN_CHUNK];            // 16 KB
    __shared__ ushort_t ebuck[BIN_CHUNK];          // 4 KB

    int base = (blockIdx.x - g_conv) * BIN_CHUNK;
    ccnt[t] = 0;
    __syncthreads();

    int   myrow[BIN_CHUNK / 512];
    int   mycol[BIN_CHUNK / 512];
    float myval[BIN_CHUNK / 512];
#pragma unroll
    for (int k = 0; k < BIN_CHUNK / 512; k++) {
        int idx = base + k * 512 + t;
        int r = (idx < nnz) ? rows[idx] : -1;
        myrow[k] = r;
        if (r >= 0) {
            mycol[k] = cols[idx];
            myval[k] = vals[idx];
            atomicAdd(&ccnt[r >> ROW_SHIFT], 1);
        }
    }
    __syncthreads();

    int c = ccnt[t];
    int excl, total;
    scan512(c, t, wsum, &excl, &total);            // 2 barriers
    cpos[t] = excl;
    __syncthreads();

#pragma unroll
    for (int k = 0; k < BIN_CHUNK / 512; k++) {
        int r = myrow[k];
        if (r >= 0) {
            int b = r >> ROW_SHIFT;
            int lrow = r & (ROWS_PER_BUCKET - 1);
            int slot = atomicAdd(&cpos[b], 1);
            entries[slot] = make_int2(mycol[k] | (lrow << 18), __float_as_int(myval[k]));
            ebuck[slot] = (ushort_t)b;
        }
    }
    __syncthreads();

    // reserve space in each touched bucket's fixed region
    // (cpos[b] now == excl[b] + ccnt[b], so cpos-ccnt == local run base)
    if (t < B_BUCKETS && ccnt[t] > 0) {
        int g = atomicAdd(&cursor[t], ccnt[t]);
        gdst[t] = t * cap + g - (cpos[t] - ccnt[t]);
    }
    __syncthreads();

    for (int i = t; i < total; i += 512) {
        int eb = ebuck[i];
        int pos = gdst[eb] + i;
        if (pos < (eb + 1) * cap)                     // capacity guard (never hits)
            staging[pos] = entries[i];
    }
}

// ---------------------------------------------------------------------------
// k_hist (UNCHANGED): full-occupancy per-(bucket,chunk) row histogram into a
// PRIVATE slot H[b][k][.] — no global atomics.
// ---------------------------------------------------------------------------
__global__ void __launch_bounds__(512) k_hist(const int2* __restrict__ staging,
                                              const int* __restrict__ cursor,
                                              int* __restrict__ H,
                                              int cap, int chunks) {
    __shared__ int h[ROWS_PER_BUCKET];
    int b = blockIdx.x / chunks;
    int k = blockIdx.x - b * chunks;
    int t = threadIdx.x;
    h[t] = 0;
    __syncthreads();
    int cnt_b = cursor[b];
    if (cnt_b > cap) cnt_b = cap;
    int hi = k * PLACE_CHUNK + PLACE_CHUNK;
    if (hi > cnt_b) hi = cnt_b;
    int rbase = b * cap;
#pragma unroll 1
    for (int i = k * PLACE_CHUNK + t; i < hi; i += 512)
        atomicAdd(&h[staging[rbase + i].x >> 18], 1);
    __syncthreads();
    H[(size_t)blockIdx.x * ROWS_PER_BUCKET + t] = h[t];
}

// ---------------------------------------------------------------------------
// k_scan2 (R20: shfl scan): one block per bucket; sums H across chunks,
// bucket-wide exclusive scan -> ranges; rewrites H to per-(chunk,row) start
// cursors.
// ---------------------------------------------------------------------------
__global__ void __launch_bounds__(512) k_scan2(int* __restrict__ H,
                                               int2* __restrict__ ranges,
                                               int cap, int chunks) {
    __shared__ int wsum[8];
    int b = blockIdx.x;
    int t = threadIdx.x;
    size_t base = (size_t)b * chunks * ROWS_PER_BUCKET + t;
    int c = 0;
#pragma unroll 1
    for (int k = 0; k < chunks; k++) c += H[base + (size_t)k * ROWS_PER_BUCKET];
    int excl, total;
    scan512(c, t, wsum, &excl, &total);
    (void)total;
    int row = (b << ROW_SHIFT) + t;
    int beg = b * cap + excl;
    if (row < N_NODES) ranges[row] = make_int2(beg, beg + c);
    int s = beg;
#pragma unroll 1
    for (int k = 0; k < chunks; k++) {
        int hh = H[base + (size_t)k * ROWS_PER_BUCKET];
        H[base + (size_t)k * ROWS_PER_BUCKET] = s;
        s += hh;
    }
}

// ---------------------------------------------------------------------------
// k_place2 (UNCHANGED): full-occupancy placement via LDS cursors; writes
// confined to the bucket's ~147 KB cv window -> L2-merged.
// ---------------------------------------------------------------------------
__global__ void __launch_bounds__(512) k_place2(const int2* __restrict__ staging,
                                                const int* __restrict__ cursor,
                                                const int* __restrict__ H,
                                                int2* __restrict__ cv,
                                                int cap, int chunks) {
    __shared__ int c[ROWS_PER_BUCKET];
    int b = blockIdx.x / chunks;
    int k = blockIdx.x - b * chunks;
    int t = threadIdx.x;
    c[t] = H[(size_t)blockIdx.x * ROWS_PER_BUCKET + t];
    __syncthreads();
    int cnt_b = cursor[b];
    if (cnt_b > cap) cnt_b = cap;
    int hi = k * PLACE_CHUNK + PLACE_CHUNK;
    if (hi > cnt_b) hi = cnt_b;
    int rbase = b * cap;
#pragma unroll 1
    for (int i = k * PLACE_CHUNK + t; i < hi; i += 512) {
        int2 e = staging[rbase + i];
        int pos = atomicAdd(&c[e.x >> 18], 1);
        cv[pos] = make_int2(e.x & COL_MASK, e.y);
    }
}

// ---------------------------------------------------------------------------
// R16 readlane-broadcast SpMM row body (UNCHANGED — verified 87.5 us x3).
// ---------------------------------------------------------------------------
#define ISSUE8(R, J0)                                                         \
    _Pragma("unroll")                                                         \
    for (int j = 0; j < 8; j++) {                                             \
        int sc = __builtin_amdgcn_readlane(vc, (J0) + j);                     \
        R[j] = xb[((size_t)(uint_t)sc << 6) + lane];                          \
    }

#define CONS8(R, J0)                                                          \
    _Pragma("unroll")                                                         \
    for (int j = 0; j < 8; j++) {                                             \
        float sv = __uint_as_float((uint_t)__builtin_amdgcn_readlane(vv, (J0) + j)); \
        acc += sv * __uint_as_float((uint_t)R[j] << 16);                      \
    }

__device__ __forceinline__ float spmm_row_rl(int beg, int end, int lane,
                                             const int2* __restrict__ cv,
                                             const ushort_t* __restrict__ xb) {
    float acc = 0.f;
#pragma unroll 1
    for (int b = beg; b < end; b += 64) {
        int2 ed = cv[b + lane];              // coalesced 512B, 1 vmcnt entry
        bool lv = (b + lane) < end;
        int vc = lv ? ed.x : 0;              // per-lane clamp (2 cndmask)
        int vv = lv ? ed.y : 0;
        int rem = end - b;                   // wave-uniform
        if (rem > 64) rem = 64;

        ushort_t q0[8], q1[8], q2[8], q3[8];
        // ---- half 0: edges 0..31 ----
        ISSUE8(q0, 0)
        if (rem > 8)  { ISSUE8(q1, 8)  }
        if (rem > 16) { ISSUE8(q2, 16) }
        if (rem > 24) { ISSUE8(q3, 24) }
        CONS8(q0, 0)
        if (rem > 8)  { CONS8(q1, 8)  }
        if (rem > 16) { CONS8(q2, 16) }
        if (rem > 24) { CONS8(q3, 24) }
        // ---- half 1: edges 32..63 ----
        if (rem > 32) {
            ISSUE8(q0, 32)
            if (rem > 40) { ISSUE8(q1, 40) }
            if (rem > 48) { ISSUE8(q2, 48) }
            if (rem > 56) { ISSUE8(q3, 56) }
            CONS8(q0, 32)
            if (rem > 40) { CONS8(q1, 40) }
            if (rem > 48) { CONS8(q2, 48) }
            if (rem > 56) { CONS8(q3, 56) }
        }
    }
    return acc;
}

__global__ void k_spmm(const int2* __restrict__ ranges, const int2* __restrict__ cv,
                       const ushort_t* __restrict__ xb, ushort_t* __restrict__ out) {
    int row = (blockIdx.x * blockDim.x + threadIdx.x) >> 6;
    int lane = threadIdx.x & 63;
    if (row >= N_NODES) return;
    row = __builtin_amdgcn_readfirstlane(row);
    int2 rng = ranges[row];
    int beg = __builtin_amdgcn_readfirstlane(rng.x);
    int end = __builtin_amdgcn_readfirstlane(rng.y);
    float a = spmm_row_rl(beg, end, lane, cv, xb);
    out[(size_t)row * 64 + lane] = f32_to_bf16(a);   // 64 lanes x 2B = 128B
}

// ---------------------------------------------------------------------------
// k_last (R20): one wave per (batch element, side) — halves the serial
// spmm_row depth vs the old two-calls-per-wave version. Wave pairs
// (user, item) share a block; user vector crosses via LDS; item wave does
// the dot. All waves hit the barrier (invalid ones idle through it).
// ---------------------------------------------------------------------------
__global__ void k_last(const int2* __restrict__ ranges, const int2* __restrict__ cv,
                       const int* __restrict__ users, const int* __restrict__ items,
                       const float* __restrict__ ue, const float* __restrict__ ie,
                       const ushort_t* __restrict__ xbA, const ushort_t* __restrict__ xbB,
                       float* __restrict__ out, int batch) {
    __shared__ float uv[2][64];
    int lane  = threadIdx.x & 63;
    int lwave = threadIdx.x >> 6;            // 0..3
    int gwave = (int)blockIdx.x * 4 + lwave;
    int w     = gwave >> 1;                  // batch element
    int side  = gwave & 1;                   // 0=user, 1=item
    bool valid = w < batch;

    int beg = 0, end = 0, row = 0, idxv = 0;
    if (valid) {
        idxv = __builtin_amdgcn_readfirstlane(side ? items[w] : users[w]);
        row  = side ? NUM_USERS + idxv : idxv;
        int2 rng = ranges[row];
        beg = __builtin_amdgcn_readfirstlane(rng.x);
        end = __builtin_amdgcn_readfirstlane(rng.y);
    }
    float a = spmm_row_rl(beg, end, lane, cv, xbB);   // beg==end -> no work

    float x_ = 0.f;
    if (valid) {
        float e = side ? ie[(size_t)idxv * EMBED_DIM + lane]
                       : ue[(size_t)idxv * EMBED_DIM + lane];
        float A = bf16_to_f32(xbA[(size_t)row * 64 + lane]);
        float B = bf16_to_f32(xbB[(size_t)row * 64 + lane]);
        x_ = e + A + B + a;
    }
    int slot = lwave >> 1;                   // 0..1 (pair within block)
    if (valid && side == 0) uv[slot][lane] = x_;
    __syncthreads();
    if (valid && side == 1) {
        float p = x_ * uv[slot][lane];
#pragma unroll
        for (int d = 32; d > 0; d >>= 1) p += __shfl_down(p, d, 64);
        if (lane == 0) out[w] = p * (1.0f / 16.0f);   // 1/16 mean^2 scale
    }
}

// ---------------------------------------------------------------------------

extern "C" void kernel_launch(void* const* d_in, const int* in_sizes, int n_in,
                              void* d_out, int out_size, void* d_ws, size_t ws_size,
                              hipStream_t stream) {
    const int*   users    = (const int*)  d_in[0];
    const int*   items    = (const int*)  d_in[1];
    const int*   adj_rows = (const int*)  d_in[2];
    const int*   adj_cols = (const int*)  d_in[3];
    const float* adj_vals = (const float*)d_in[4];
    const float* user_emb = (const float*)d_in[5];
    const float* item_emb = (const float*)d_in[6];
    float* out = (float*)d_out;

    const int batch = in_sizes[0];
    const int nnz   = in_sizes[2];

    // fixed bucket capacity: mean * 9/8, rounded up to 64 (16-sigma margin)
    int cap = ((nnz / B_BUCKETS) * 9 + 7) / 8;
    cap = (cap + 63) & ~63;
    const size_t padded = (size_t)B_BUCKETS * cap;   // ~5.4M entries
    const int chunks = (cap + PLACE_CHUNK - 1) / PLACE_CHUNK;     // ~9

    char* p = (char*)d_ws;
    auto alloc = [&](size_t bytes) -> char* {
        char* r = p;
        p += (bytes + 255) & ~(size_t)255;
        return r;
    };
    const size_t xb_bytes = (size_t)N_NODES * EMBED_DIM * 2;       // 19.2 MB
    int2*     ranges = (int2*) alloc((size_t)N_NODES * 8);
    int*      cursor = (int*)  alloc(NBP * 4);
    int*      H      = (int*)  alloc((size_t)B_BUCKETS * chunks * ROWS_PER_BUCKET * 4); // 5.4 MB
    int2*     cv     = (int2*) alloc(padded * 8);                  // padded CSR
    // region overlays: staging (build) vs xbA+xbB (layer buffers)
    size_t    region_bytes = padded * 8;
    if (region_bytes < 2 * xb_bytes) region_bytes = 2 * xb_bytes;
    char*     region  = alloc(region_bytes);
    int2*     staging = (int2*)region;
    ushort_t* xbA     = (ushort_t*)region;
    ushort_t* xbB     = (ushort_t*)(region + xb_bytes);
    ushort_t* xb_ego  = (ushort_t*)alloc(xb_bytes);

    const int g_conv  = ((N_NODES * EMBED_DIM / 4) + 511) / 512;   // 4688
    const int g_bin   = (nnz + BIN_CHUNK - 1) / BIN_CHUNK;         // 2344
    const int g_nodes = (N_NODES + 3) / 4;                         // 4 waves/block
    const int g_last  = (2 * batch + 3) / 4;                       // wave pairs

    // ---- build: bin -> per-chunk hist -> scan -> place (no global atomics
    // on the edge-hot path anywhere) ----
    hipMemsetAsync(cursor, 0, NBP * 4, stream);
    k_bin2<<<g_conv + g_bin, 512, 0, stream>>>(user_emb, item_emb, xb_ego,
                                               adj_rows, adj_cols, adj_vals,
                                               cursor, staging, nnz, cap, g_conv);
    k_hist<<<B_BUCKETS * chunks, 512, 0, stream>>>(staging, cursor, H, cap, chunks);
    k_scan2<<<B_BUCKETS, 512, 0, stream>>>(H, ranges, cap, chunks);
    k_place2<<<B_BUCKETS * chunks, 512, 0, stream>>>(staging, cursor, H, cv,
                                                     cap, chunks);

    // ---- layer 1: xbA = A * ego ----
    k_spmm<<<g_nodes, 256, 0, stream>>>(ranges, cv, xb_ego, xbA);

    // ---- layer 2: xbB = A * xbA ----
    k_spmm<<<g_nodes, 256, 0, stream>>>(ranges, cv, xbA, xbB);

    // ---- layer 3 (batch rows only) + gather + dot, fused ----
    k_last<<<g_last, 256, 0, stream>>>(ranges, cv, users, items,
                                       user_emb, item_emb, xbA, xbB, out, batch);
}